// Round 16
// baseline (660.465 us; speedup 1.0000x reference)
//
#include <hip/hip_runtime.h>
#include <hip/hip_bf16.h>

// N=65536 points, H=256, 4 hidden layers, ReLU MLP -> (psi,p).
// ReLU => piecewise linear => Hessians vanish; f = p_x, g = p_y (RHO=1).
// v16: ONE fused kernel per 128 points:
//   Phase 1 = v11 forward VERBATIM (np/BLAS bit-exact fp32 chain, masks+p;
//             1024 thr = 16 waves x 16 cols, 2 pts/lane, wave-uniform s_load).
//   Phase 2 = in-block tangent chain: LDS hT region reused as Apan (256 rows
//             = 128 pts x {x,y} tangents, f16), W staged in 32-k chunks,
//             mask-gated per layer (masks re-read from global, same-block RAW),
//             fused finalize -> u,v,f,g. Same k-ascending MFMA accumulation
//             order as v7/v15 -> bit-identical outputs.
// Kills: tangent launch, T init/finalize traffic, and runs tangent at
// 16 waves/CU (was 8). LDS union 155.6 KB (1 block/CU, as v11 already was).
// Workspace: masks 5x2MB | Wt 512KB

#define NPTS 65536
#define HDIM 256

typedef _Float16 half8_t __attribute__((ext_vector_type(8)));
typedef _Float16 half4_t __attribute__((ext_vector_type(4)));
typedef float floatx4 __attribute__((ext_vector_type(4)));

// ---------------------------------------------------------------- prep: Wh fp32 [l][k][n] -> f16 [l][n][k]
__global__ void __launch_bounds__(256) prep_weights_kernel(
    const float* __restrict__ Wh, _Float16* __restrict__ Wt) {
  int i = blockIdx.x * 256 + threadIdx.x;   // 0..262143
  int l = i >> 16;
  int rem = i & 65535;
  int k = rem >> 8, n = rem & 255;
  Wt[(size_t)(l << 16) + n * 256 + k] = (_Float16)Wh[i];
}

// ---------------------------------------------------------------- fused forward + tangent kernel
// 1024 threads = 16 waves, 128 pts/block, 512 blocks.
// LDS union (155648 B):
//   phase 1: hT = float[128*257] @0 (131584) | pscr = float[16*132] @131584 (8448)
//   phase 2: Apan = f16[256*264] @0 (135168) | Bpan/mbuf @135168 (20480)
__global__ void __launch_bounds__(1024) fused_all_kernel(
    const float* __restrict__ x, const float* __restrict__ y, const float* __restrict__ t,
    const float* __restrict__ Win, const float* __restrict__ b_in,
    const float* __restrict__ Wh, const float* __restrict__ b_h,
    const float* __restrict__ Wout, const float* __restrict__ b_out,
    const _Float16* __restrict__ Wt, unsigned int* __restrict__ maskDw,
    float* __restrict__ out) {
  constexpr int SH = 257;              // fwd hT stride (odd -> conflict-free b32)
  constexpr int SA = 264;              // Apan row stride (halves), 16B-aligned rows
  constexpr int SB = 40;               // Bpan row stride (halves) for 32-k chunks
  __shared__ __attribute__((aligned(16))) char smem[155648];
  float* hT = (float*)smem;                          // [pt][k]
  float* pscr = (float*)(smem + 131584);             // [16][132]
  _Float16* Apan = (_Float16*)smem;                  // [256][SA]
  _Float16* Bpan = (_Float16*)(smem + 135168);       // [256][SB]
  unsigned int* mbuf = (unsigned int*)(smem + 135168);  // 1024 dw (aliases Bpan)

  const int tid = threadIdx.x;
  const int lane = tid & 63;
  const int w = __builtin_amdgcn_readfirstlane(tid >> 6);   // wave id 0..15
  const int c0 = w * 16;
  const int p0 = blockIdx.x * 128;
  const int pA = p0 + lane;
  const int pB = p0 + 64 + lane;
  unsigned char* masks = (unsigned char*)maskDw;

  // ================= PHASE 1: fp32 forward, np/BLAS bit-exact (v11 verbatim)
  {
    float xa = x[pA], ya = y[pA], ta = t[pA];
    float xb = x[pB], yb = y[pB], tb = t[pB];
    unsigned ma = 0, mb = 0;
#pragma unroll
    for (int e = 0; e < 16; ++e) {
      int c = c0 + e;                  // uniform -> Win reads are scalar
      float w0 = Win[c], w1 = Win[256 + c], w2 = Win[512 + c], bb = b_in[c];
      float da = fmaf(xa, w0, 0.f);
      da = fmaf(ya, w1, da);
      da = fmaf(ta, w2, da);
      float aa = da + bb;
      bool posa = aa > 0.f;
      hT[lane * SH + c] = posa ? aa : 0.f;
      ma |= (posa ? 1u : 0u) << e;
      float db = fmaf(xb, w0, 0.f);
      db = fmaf(yb, w1, db);
      db = fmaf(tb, w2, db);
      float ab = db + bb;
      bool posb = ab > 0.f;
      hT[(64 + lane) * SH + c] = posb ? ab : 0.f;
      mb |= (posb ? 1u : 0u) << e;
    }
    *(unsigned short*)(masks + (size_t)pA * 32 + w * 2) = (unsigned short)ma;
    *(unsigned short*)(masks + (size_t)pB * 32 + w * 2) = (unsigned short)mb;
  }
  __syncthreads();

  for (int l = 0; l < 4; ++l) {
    const float* Wl = Wh + (size_t)l * 65536 + c0;   // + uniform col offset
    float accA[16] = {};
    float accB[16] = {};
#pragma unroll 2
    for (int k = 0; k < 256; ++k) {
      float hA = hT[lane * SH + k];          // per-lane LDS, conflict-free
      float hB = hT[(64 + lane) * SH + k];
      const float* wr = Wl + k * 256;        // wave-uniform -> s_load_dwordx16
#pragma unroll
      for (int e = 0; e < 16; ++e) {
        float wv = wr[e];
        accA[e] = fmaf(hA, wv, accA[e]);
        accB[e] = fmaf(hB, wv, accB[e]);
      }
    }
    __syncthreads();                   // all hT reads done before overwrite
    unsigned ma = 0, mb = 0;
    float hnA[16], hnB[16];
#pragma unroll
    for (int e = 0; e < 16; ++e) {
      float bb = b_h[l * 256 + c0 + e];
      float aa = accA[e] + bb;
      bool posa = aa > 0.f;
      hnA[e] = posa ? aa : 0.f;
      ma |= (posa ? 1u : 0u) << e;
      float ab = accB[e] + bb;
      bool posb = ab > 0.f;
      hnB[e] = posb ? ab : 0.f;
      mb |= (posb ? 1u : 0u) << e;
    }
    *(unsigned short*)(masks + ((size_t)(l + 1) * NPTS + pA) * 32 + w * 2) =
        (unsigned short)ma;
    *(unsigned short*)(masks + ((size_t)(l + 1) * NPTS + pB) * 32 + w * 2) =
        (unsigned short)mb;
#pragma unroll
    for (int e = 0; e < 16; ++e) {
      hT[lane * SH + c0 + e] = hnA[e];
      hT[(64 + lane) * SH + c0 + e] = hnB[e];
    }
    __syncthreads();
  }

  // p = h5 . Wout[:,1] + b_out[1]
  {
    float sA = 0.f, sB = 0.f;
#pragma unroll
    for (int e = 0; e < 16; ++e) {
      float wv = Wout[2 * (c0 + e) + 1];
      sA = fmaf(hT[lane * SH + c0 + e], wv, sA);
      sB = fmaf(hT[(64 + lane) * SH + c0 + e], wv, sB);
    }
    pscr[w * 132 + lane] = sA;
    pscr[w * 132 + 64 + lane] = sB;
  }
  __syncthreads();
  if (tid < 128) {
    float s2 = 0.f;
#pragma unroll
    for (int g = 0; g < 16; ++g) s2 += pscr[g * 132 + tid];
    out[2 * NPTS + p0 + tid] = s2 + b_out[1];
  }
  __syncthreads();                     // hT/pscr dead; LDS becomes Apan/Bpan

  // ================= PHASE 2: tangent chain (256 rows x 256 cols, f16 MFMA)
  // rows 0..127 = x-tangent of pts p0..p0+127; rows 128..255 = y-tangent.
  // wave grid: rg = w>>2 (row group, 64 rows), cg = w&3 (col group, 64 cols).
  const int rg = w >> 2, cg = w & 3;
  const int l15 = lane & 15, quad = lane >> 4;

  // ---- stage mask layer 0, then init T1 into Apan
  mbuf[tid] = maskDw[(size_t)p0 * 8 + tid];
  __syncthreads();
#pragma unroll
  for (int i = 0; i < 8; ++i) {
    int g = tid + 1024 * i;            // 0..8191 col-groups of 8
    int row = g >> 5, cg8 = g & 31;
    int cc = cg8 * 8, pt = row & 127, tg = row >> 7;
    unsigned dw = mbuf[pt * 8 + (cc >> 5)];
    half8_t v;
#pragma unroll
    for (int e = 0; e < 8; ++e) {
      bool m = (dw >> ((cg8 & 3) * 8 + e)) & 1;
      v[e] = m ? (_Float16)Win[tg * 256 + cc + e] : (_Float16)0.f;
    }
    *(half8_t*)&Apan[row * SA + cc] = v;
  }
  __syncthreads();

  // ---- 4 layers
  for (int l = 0; l < 4; ++l) {
    const _Float16* Wl = Wt + (size_t)l * 65536;
    floatx4 acc[4][4] = {};   // [mi][nj]
#pragma unroll
    for (int kc = 0; kc < 8; ++kc) {   // 32-k chunks, ascending
      __syncthreads();                 // Bpan free
      // stage B chunk: n = tid>>2 (0..255), seg = tid&3 (8 halves each)
      {
        int n = tid >> 2, seg = tid & 3;
        *(half8_t*)&Bpan[n * SB + seg * 8] =
            *(const half8_t*)(Wl + (size_t)n * 256 + kc * 32 + seg * 8);
      }
      __syncthreads();
      half8_t af[4], bf[4];
#pragma unroll
      for (int mi = 0; mi < 4; ++mi)
        af[mi] = *(const half8_t*)&Apan[(rg * 64 + mi * 16 + l15) * SA + kc * 32 + quad * 8];
#pragma unroll
      for (int nj = 0; nj < 4; ++nj)
        bf[nj] = *(const half8_t*)&Bpan[(cg * 64 + nj * 16 + l15) * SB + quad * 8];
#pragma unroll
      for (int mi = 0; mi < 4; ++mi)
#pragma unroll
        for (int nj = 0; nj < 4; ++nj)
          acc[mi][nj] = __builtin_amdgcn_mfma_f32_16x16x32_f16(af[mi], bf[nj], acc[mi][nj], 0, 0, 0);
    }
    __syncthreads();          // B dead; stage mask layer l+1 into mbuf
    mbuf[tid] = maskDw[((size_t)(l + 1) * NPTS + p0) * 8 + tid];
    __syncthreads();          // masks ready; also fences Apan reads (af done)
    // gated write-back (C layout -> A storage), f16
#pragma unroll
    for (int mi = 0; mi < 4; ++mi) {
#pragma unroll
      for (int r = 0; r < 4; ++r) {
        int row = rg * 64 + mi * 16 + quad * 4 + r;
        int pt = row & 127;
#pragma unroll
        for (int nj = 0; nj < 4; ++nj) {
          int C = cg * 64 + nj * 16 + l15;
          bool m = (mbuf[pt * 8 + (C >> 5)] >> (C & 31)) & 1;
          Apan[row * SA + C] = m ? (_Float16)acc[mi][nj][r] : (_Float16)0.f;
        }
      }
    }
    __syncthreads();
  }

  // ---- finalize from Apan (= T5 gated): wave w handles rows w*16..+15
  {
    float4 wA = *(const float4*)(Wout + lane * 8);   // (W[c][0],W[c][1],W[c+1][0],W[c+1][1])
    float4 wB = *(const float4*)(Wout + lane * 8 + 4);
    float w0[4] = {wA.x, wA.z, wB.x, wB.z};  // Wout[:,0] for cols lane*4..+3
    float w1[4] = {wA.y, wA.w, wB.y, wB.w};  // Wout[:,1]
#pragma unroll
    for (int i = 0; i < 16; ++i) {
      int row = w * 16 + i;
      half4_t hv = *(const half4_t*)&Apan[row * SA + lane * 4];
      float s0 = 0.f, s1 = 0.f;
#pragma unroll
      for (int e = 0; e < 4; ++e) {
        float fv = (float)hv[e];
        s0 = fmaf(fv, w0[e], s0);
        s1 = fmaf(fv, w1[e], s1);
      }
#pragma unroll
      for (int off = 1; off < 64; off <<= 1) {
        s0 += __shfl_xor(s0, off);
        s1 += __shfl_xor(s1, off);
      }
      if (lane == 0) {
        int pt = p0 + (row & 127);
        if (row < 128) {               // x-tangent: v = -psi_x, f = p_x
          out[NPTS + pt] = -s0;
          out[3 * NPTS + pt] = s1;
        } else {                       // y-tangent: u = psi_y, g = p_y
          out[pt] = s0;
          out[4 * NPTS + pt] = s1;
        }
      }
    }
  }
}

// ---------------------------------------------------------------- launch
extern "C" void kernel_launch(void* const* d_in, const int* in_sizes, int n_in,
                              void* d_out, int out_size, void* d_ws, size_t ws_size,
                              hipStream_t stream) {
  const float* x = (const float*)d_in[0];
  const float* y = (const float*)d_in[1];
  const float* t = (const float*)d_in[2];
  const float* Win = (const float*)d_in[3];
  const float* b_in = (const float*)d_in[4];
  const float* Wh = (const float*)d_in[5];
  const float* b_h = (const float*)d_in[6];
  const float* Wout = (const float*)d_in[7];
  const float* b_out = (const float*)d_in[8];
  float* out = (float*)d_out;

  char* ws = (char*)d_ws;
  constexpr size_t MASK_SZ = (size_t)NPTS * 32;       // 2 MB per layer
  unsigned int* masks = (unsigned int*)ws;
  _Float16* Wt = (_Float16*)(ws + 5 * MASK_SZ);

  // weight transpose/cast (must precede fused kernel's phase 2)
  prep_weights_kernel<<<1024, 256, 0, stream>>>(Wh, Wt);

  // fused: np-exact forward (masks + p) then in-block tangent chain (u,v,f,g)
  fused_all_kernel<<<NPTS / 128, 1024, 0, stream>>>(
      x, y, t, Win, b_in, Wh, b_h, Wout, b_out, Wt, masks, out);
}

// Round 18
// 557.612 us; speedup vs baseline: 1.1845x; 1.1845x over previous
//
#include <hip/hip_runtime.h>
#include <hip/hip_bf16.h>

// N=65536 points, H=256, 4 hidden layers, ReLU MLP -> (psi,p).
// ReLU => piecewise linear => Hessians vanish; f = p_x, g = p_y (RHO=1).
// Pipeline:
//   1) fp32 forward replicating np/BLAS arithmetic BIT-EXACTLY (v11 kernel,
//      UNMODIFIED; ~403 us; dual-bound by scalar-FMA issue (~218us) and
//      scalar-K$ supply (~203us) which cannot both be relieved - v6..v14
//      explored occupancy/VMEM/packing/pts-per-lane).
//   2) v18 fused tangent kernel: v15's wave-private B staging (padded LDS,
//      plain loads - v17's global_load_lds DMA corrupted results, reverted)
//      + SOFTWARE PIPELINE: next kp chunk prefetched into VGPRs during the
//      current chunk's MFMA phase, committed to LDS next iteration. Same
//      values, same MFMA order -> bit-identical outputs to v15.
// Workspace: masks 5x2MB | Wt 512KB

#define NPTS 65536
#define HDIM 256

typedef _Float16 half8_t __attribute__((ext_vector_type(8)));
typedef _Float16 half4_t __attribute__((ext_vector_type(4)));
typedef float floatx4 __attribute__((ext_vector_type(4)));

// ---------------------------------------------------------------- fused fp32 forward (np/BLAS-exact) — v11 verbatim
__global__ void __launch_bounds__(1024) fwd_fused_kernel(
    const float* __restrict__ x, const float* __restrict__ y, const float* __restrict__ t,
    const float* __restrict__ Win, const float* __restrict__ b_in,
    const float* __restrict__ Wh, const float* __restrict__ b_h,
    const float* __restrict__ Wout, const float* __restrict__ b_out,
    unsigned char* __restrict__ masks, float* __restrict__ out) {
  constexpr int SH = 257;              // odd stride: conflict-free b32
  __shared__ float hT[128 * SH];       // [pt][k]  131584 B
  __shared__ float pscr[16][132];      // wave partials for p (8448 B)

  const int tid = threadIdx.x;
  const int lane = tid & 63;
  const int w = __builtin_amdgcn_readfirstlane(tid >> 6);       // wave id 0..15
  const int c0 = w * 16;                                        // 16-col group
  const int p0 = blockIdx.x * 128;
  const int pA = p0 + lane;            // point A
  const int pB = p0 + 64 + lane;       // point B

  // ---- layer 1: dot = z @ Win (k ascending: x,y,t), then + b_in  [bit-exact]
  {
    float xa = x[pA], ya = y[pA], ta = t[pA];
    float xb = x[pB], yb = y[pB], tb = t[pB];
    unsigned ma = 0, mb = 0;
#pragma unroll
    for (int e = 0; e < 16; ++e) {
      int c = c0 + e;                  // uniform -> Win reads are scalar
      float w0 = Win[c], w1 = Win[256 + c], w2 = Win[512 + c], bb = b_in[c];
      float da = fmaf(xa, w0, 0.f);
      da = fmaf(ya, w1, da);
      da = fmaf(ta, w2, da);
      float aa = da + bb;
      bool posa = aa > 0.f;
      hT[lane * SH + c] = posa ? aa : 0.f;
      ma |= (posa ? 1u : 0u) << e;
      float db = fmaf(xb, w0, 0.f);
      db = fmaf(yb, w1, db);
      db = fmaf(tb, w2, db);
      float ab = db + bb;
      bool posb = ab > 0.f;
      hT[(64 + lane) * SH + c] = posb ? ab : 0.f;
      mb |= (posb ? 1u : 0u) << e;
    }
    *(unsigned short*)(masks + (size_t)pA * 32 + w * 2) = (unsigned short)ma;
    *(unsigned short*)(masks + (size_t)pB * 32 + w * 2) = (unsigned short)mb;
  }
  __syncthreads();

  // ---- hidden layers: single fp32 accumulator per element, k ascending, fmaf
  for (int l = 0; l < 4; ++l) {
    const float* Wl = Wh + (size_t)l * 65536 + c0;   // + uniform col offset
    float accA[16] = {};
    float accB[16] = {};
#pragma unroll 2
    for (int k = 0; k < 256; ++k) {
      float hA = hT[lane * SH + k];          // per-lane LDS, conflict-free
      float hB = hT[(64 + lane) * SH + k];
      const float* wr = Wl + k * 256;        // wave-uniform -> s_load_dwordx16
#pragma unroll
      for (int e = 0; e < 16; ++e) {
        float wv = wr[e];
        accA[e] = fmaf(hA, wv, accA[e]);
        accB[e] = fmaf(hB, wv, accB[e]);
      }
    }
    __syncthreads();                   // all hT reads done before overwrite
    unsigned ma = 0, mb = 0;
    float hnA[16], hnB[16];
#pragma unroll
    for (int e = 0; e < 16; ++e) {
      float bb = b_h[l * 256 + c0 + e];
      float aa = accA[e] + bb;
      bool posa = aa > 0.f;
      hnA[e] = posa ? aa : 0.f;
      ma |= (posa ? 1u : 0u) << e;
      float ab = accB[e] + bb;
      bool posb = ab > 0.f;
      hnB[e] = posb ? ab : 0.f;
      mb |= (posb ? 1u : 0u) << e;
    }
    *(unsigned short*)(masks + ((size_t)(l + 1) * NPTS + pA) * 32 + w * 2) =
        (unsigned short)ma;
    *(unsigned short*)(masks + ((size_t)(l + 1) * NPTS + pB) * 32 + w * 2) =
        (unsigned short)mb;
#pragma unroll
    for (int e = 0; e < 16; ++e) {
      hT[lane * SH + c0 + e] = hnA[e];
      hT[(64 + lane) * SH + c0 + e] = hnB[e];
    }
    __syncthreads();
  }

  // ---- p = h5 . Wout[:,1] + b_out[1]
  {
    float sA = 0.f, sB = 0.f;
#pragma unroll
    for (int e = 0; e < 16; ++e) {
      float wv = Wout[2 * (c0 + e) + 1];
      sA = fmaf(hT[lane * SH + c0 + e], wv, sA);
      sB = fmaf(hT[(64 + lane) * SH + c0 + e], wv, sB);
    }
    pscr[w][lane] = sA;
    pscr[w][64 + lane] = sB;
  }
  __syncthreads();
  if (tid < 128) {
    float s2 = 0.f;
#pragma unroll
    for (int g = 0; g < 16; ++g) s2 += pscr[g][tid];
    out[2 * NPTS + p0 + tid] = s2 + b_out[1];
  }
}

// ---------------------------------------------------------------- prep: Wh fp32 [l][k][n] -> f16 [l][n][k]
__global__ void __launch_bounds__(256) prep_weights_kernel(
    const float* __restrict__ Wh, _Float16* __restrict__ Wt) {
  int i = blockIdx.x * 256 + threadIdx.x;   // 0..262143
  int l = i >> 16;
  int rem = i & 65535;
  int k = rem >> 8, n = rem & 255;
  Wt[(size_t)(l << 16) + n * 256 + k] = (_Float16)Wh[i];
}

// ---------------------------------------------------------------- fused tangent chain (init + 4 layers + finalize)
// Block: 256 thr = 4 waves. 32 points -> 64 rows (0..31 x-tangent, 32..63 y).
// Tile M=64 x N=256; wave wn owns 64 rows x 64 cols (acc 4x4 16x16 tiles).
// T lives in Apan (f16) across layers. v18: wave-private B staging (padded,
// plain loads) with a VGPR prefetch pipeline: chunk kp+1 is loaded into
// breg[] before kp's MFMA phase and committed to LDS at the top of the next
// iteration. No barriers in the kp loop (within-wave lgkmcnt ordering).
// mfma_f32_16x16x32_f16: A[m=lane&15][k=quad*8+j], B[k=quad*8+j][n=lane&15],
//                        D[row=quad*4+reg][col=lane&15]  (verified layouts)
__global__ void __launch_bounds__(256, 2) tangent_fused_kernel(
    const float* __restrict__ Win,
    const _Float16* __restrict__ Wt,          // [l][n][k] (pre-transposed)
    const unsigned int* __restrict__ maskDw,  // [5][NPTS][8] dwords
    const float* __restrict__ Wout, float* __restrict__ out) {
  constexpr int SA = 264;   // A row stride (halves): 256 + 8 pad
  constexpr int SB = 72;    // B row stride (halves): 64 + 8 pad
  __shared__ alignas(16) _Float16 Apan[64 * SA];        // 33792 B
  __shared__ alignas(16) _Float16 Bpan[4][64 * SB];     // 4 x 9216 B = 36864 B
  __shared__ unsigned int smask[5 * 256];               // 5120 B

  const int tid = threadIdx.x;
  const int lane = tid & 63;
  const int wn = tid >> 6;          // wave = 64-col group
  const int l15 = lane & 15, quad = lane >> 4;
  const int p0 = blockIdx.x * 32;   // 32 points per block

  // ---- stage all 5 mask layers (32 pts x 8 dw each)
#pragma unroll
  for (int i = 0; i < 5; ++i)
    smask[i * 256 + tid] = maskDw[(size_t)i * NPTS * 8 + (size_t)p0 * 8 + tid];
  __syncthreads();

  // ---- init T1 into Apan: row<32 -> x-tangent (Win row 0), row>=32 -> y (row 1)
#pragma unroll
  for (int i = 0; i < 8; ++i) {
    int g = tid + 256 * i;          // 0..2047 col-groups of 8
    int row = g >> 5, cg = g & 31;
    int c0 = cg * 8, pt = row & 31, tg = row >> 5;
    unsigned dw = smask[pt * 8 + (c0 >> 5)];
    half8_t v;
#pragma unroll
    for (int e = 0; e < 8; ++e) {
      bool m = (dw >> ((cg & 3) * 8 + e)) & 1;
      v[e] = m ? (_Float16)Win[tg * 256 + c0 + e] : (_Float16)0.f;
    }
    *(half8_t*)&Apan[row * SA + c0] = v;
  }
  __syncthreads();                  // Apan init visible to all waves

  // ---- 4 layers: acc = A @ W_l, gate by mask[l+1], back into Apan as f16
  for (int l = 0; l < 4; ++l) {
    // wave-private B slice: rows wn*64 .. wn*64+63 of Wt layer l
    const _Float16* Bw = Wt + (size_t)l * 65536 + (size_t)(wn * 64) * 256;
    _Float16* Bp = &Bpan[wn][0];
    floatx4 acc[4][4] = {};   // [mi][nj]
    half8_t breg[8];
    // prefetch chunk kp=0 into registers
#pragma unroll
    for (int i = 0; i < 8; ++i) {
      int idx = lane + 64 * i;    // 0..511 half8 segs
      int row = idx >> 3, seg = idx & 7;
      breg[i] = *(const half8_t*)(Bw + (size_t)row * 256 + seg * 8);
    }
#pragma unroll
    for (int kp = 0; kp < 4; ++kp) {
      // commit prefetched chunk to wave-private LDS (no barrier: same-wave
      // ds_write -> ds_read ordering via lgkmcnt/alias analysis)
#pragma unroll
      for (int i = 0; i < 8; ++i) {
        int idx = lane + 64 * i;
        int row = idx >> 3, seg = idx & 7;
        *(half8_t*)&Bp[row * SB + seg * 8] = breg[i];
      }
      // prefetch next chunk; its latency overlaps this chunk's MFMA phase
      if (kp < 3) {
#pragma unroll
        for (int i = 0; i < 8; ++i) {
          int idx = lane + 64 * i;
          int row = idx >> 3, seg = idx & 7;
          breg[i] = *(const half8_t*)(Bw + (size_t)row * 256 + (kp + 1) * 64 + seg * 8);
        }
      }
#pragma unroll
      for (int ks = 0; ks < 2; ++ks) {
        half8_t af[4], bf[4];
#pragma unroll
        for (int mi = 0; mi < 4; ++mi)
          af[mi] = *(const half8_t*)&Apan[(mi * 16 + l15) * SA + kp * 64 + ks * 32 + quad * 8];
#pragma unroll
        for (int nj = 0; nj < 4; ++nj)
          bf[nj] = *(const half8_t*)&Bp[(nj * 16 + l15) * SB + ks * 32 + quad * 8];
#pragma unroll
        for (int mi = 0; mi < 4; ++mi)
#pragma unroll
          for (int nj = 0; nj < 4; ++nj)
            acc[mi][nj] = __builtin_amdgcn_mfma_f32_16x16x32_f16(af[mi], bf[nj], acc[mi][nj], 0, 0, 0);
      }
    }
    __syncthreads();          // all Apan reads of this layer done
    // gated write-back (C layout -> A storage), f16
    const unsigned int* ml = &smask[(l + 1) * 256];
#pragma unroll
    for (int mi = 0; mi < 4; ++mi) {
#pragma unroll
      for (int r = 0; r < 4; ++r) {
        int row = mi * 16 + quad * 4 + r;
        int pt = row & 31;
#pragma unroll
        for (int nj = 0; nj < 4; ++nj) {
          int C = wn * 64 + nj * 16 + l15;
          bool m = (ml[pt * 8 + (C >> 5)] >> (C & 31)) & 1;
          Apan[row * SA + C] = m ? (_Float16)acc[mi][nj][r] : (_Float16)0.f;
        }
      }
    }
    __syncthreads();
  }

  // ---- finalize from Apan (= T5 gated): per row, dots with Wout cols
  float4 wA = *(const float4*)(Wout + lane * 8);      // (W[c][0],W[c][1],W[c+1][0],W[c+1][1])
  float4 wB = *(const float4*)(Wout + lane * 8 + 4);
  float w0[4] = {wA.x, wA.z, wB.x, wB.z};  // Wout[:,0] for cols lane*4..+3
  float w1[4] = {wA.y, wA.w, wB.y, wB.w};  // Wout[:,1]
#pragma unroll
  for (int i = 0; i < 16; ++i) {
    int row = wn * 16 + i;
    half4_t hv = *(const half4_t*)&Apan[row * SA + lane * 4];
    float s0 = 0.f, s1 = 0.f;
#pragma unroll
    for (int e = 0; e < 4; ++e) {
      float fv = (float)hv[e];
      s0 = fmaf(fv, w0[e], s0);
      s1 = fmaf(fv, w1[e], s1);
    }
#pragma unroll
    for (int off = 1; off < 64; off <<= 1) {
      s0 += __shfl_xor(s0, off);
      s1 += __shfl_xor(s1, off);
    }
    if (lane == 0) {
      int pt = p0 + (row & 31);
      if (row < 32) {                 // x-tangent: v = -psi_x, f = p_x
        out[NPTS + pt] = -s0;
        out[3 * NPTS + pt] = s1;
      } else {                        // y-tangent: u = psi_y, g = p_y
        out[pt] = s0;
        out[4 * NPTS + pt] = s1;
      }
    }
  }
}

// ---------------------------------------------------------------- launch
extern "C" void kernel_launch(void* const* d_in, const int* in_sizes, int n_in,
                              void* d_out, int out_size, void* d_ws, size_t ws_size,
                              hipStream_t stream) {
  const float* x = (const float*)d_in[0];
  const float* y = (const float*)d_in[1];
  const float* t = (const float*)d_in[2];
  const float* Win = (const float*)d_in[3];
  const float* b_in = (const float*)d_in[4];
  const float* Wh = (const float*)d_in[5];
  const float* b_h = (const float*)d_in[6];
  const float* Wout = (const float*)d_in[7];
  const float* b_out = (const float*)d_in[8];
  float* out = (float*)d_out;

  char* ws = (char*)d_ws;
  constexpr size_t MASK_SZ = (size_t)NPTS * 32;       // 2 MB per layer
  unsigned char* masks = (unsigned char*)ws;
  _Float16* Wt = (_Float16*)(ws + 5 * MASK_SZ);

  // weight transpose/cast first (independent of fwd)
  prep_weights_kernel<<<1024, 256, 0, stream>>>(Wh, Wt);

  // fp32 np-exact forward: masks L0..L4 + p
  fwd_fused_kernel<<<NPTS / 128, 1024, 0, stream>>>(
      x, y, t, Win, b_in, Wh, b_h, Wout, b_out, masks, out);

  // fused tangent chain: init + 4 MFMA layers + finalize (u,v,f,g)
  tangent_fused_kernel<<<NPTS / 32, 256, 0, stream>>>(
      Win, Wt, (const unsigned int*)masks, Wout, out);
}

// Round 19
// 541.650 us; speedup vs baseline: 1.2194x; 1.0295x over previous
//
#include <hip/hip_runtime.h>
#include <hip/hip_bf16.h>

// N=65536 points, H=256, 4 hidden layers, ReLU MLP -> (psi,p).
// ReLU => piecewise linear => Hessians vanish; f = p_x, g = p_y (RHO=1).
// Pipeline:
//   1) fp32 forward replicating np/BLAS arithmetic BIT-EXACTLY (v11 kernel,
//      UNMODIFIED; ~403 us; dual-bound by scalar-FMA issue and scalar-K$
//      supply - v6..v14 explored all alternatives).
//   2) v19 fused tangent kernel: LDS-OP reduction (v15/v18 were LDS-pipe
//      bound at ~1060 ops/wave):
//      a) MFMA operand swap mfma(bf,af,acc) -> transposed D layout ->
//         write-back = 16 ds_write_b64 instead of 64 ds_write_b16
//         (same products, same k order -> bit-identical values);
//      b) finalize = one MFMA chain vs 192 ds_swizzle shuffle ops
//         (Wout rounded to f16: adds ~1e-5, margin 6.5x).
// Workspace: masks 5x2MB | Wt 512KB

#define NPTS 65536
#define HDIM 256

typedef _Float16 half8_t __attribute__((ext_vector_type(8)));
typedef _Float16 half4_t __attribute__((ext_vector_type(4)));
typedef float floatx4 __attribute__((ext_vector_type(4)));

// ---------------------------------------------------------------- fused fp32 forward (np/BLAS-exact) — v11 verbatim
__global__ void __launch_bounds__(1024) fwd_fused_kernel(
    const float* __restrict__ x, const float* __restrict__ y, const float* __restrict__ t,
    const float* __restrict__ Win, const float* __restrict__ b_in,
    const float* __restrict__ Wh, const float* __restrict__ b_h,
    const float* __restrict__ Wout, const float* __restrict__ b_out,
    unsigned char* __restrict__ masks, float* __restrict__ out) {
  constexpr int SH = 257;              // odd stride: conflict-free b32
  __shared__ float hT[128 * SH];       // [pt][k]  131584 B
  __shared__ float pscr[16][132];      // wave partials for p (8448 B)

  const int tid = threadIdx.x;
  const int lane = tid & 63;
  const int w = __builtin_amdgcn_readfirstlane(tid >> 6);       // wave id 0..15
  const int c0 = w * 16;                                        // 16-col group
  const int p0 = blockIdx.x * 128;
  const int pA = p0 + lane;            // point A
  const int pB = p0 + 64 + lane;       // point B

  // ---- layer 1: dot = z @ Win (k ascending: x,y,t), then + b_in  [bit-exact]
  {
    float xa = x[pA], ya = y[pA], ta = t[pA];
    float xb = x[pB], yb = y[pB], tb = t[pB];
    unsigned ma = 0, mb = 0;
#pragma unroll
    for (int e = 0; e < 16; ++e) {
      int c = c0 + e;                  // uniform -> Win reads are scalar
      float w0 = Win[c], w1 = Win[256 + c], w2 = Win[512 + c], bb = b_in[c];
      float da = fmaf(xa, w0, 0.f);
      da = fmaf(ya, w1, da);
      da = fmaf(ta, w2, da);
      float aa = da + bb;
      bool posa = aa > 0.f;
      hT[lane * SH + c] = posa ? aa : 0.f;
      ma |= (posa ? 1u : 0u) << e;
      float db = fmaf(xb, w0, 0.f);
      db = fmaf(yb, w1, db);
      db = fmaf(tb, w2, db);
      float ab = db + bb;
      bool posb = ab > 0.f;
      hT[(64 + lane) * SH + c] = posb ? ab : 0.f;
      mb |= (posb ? 1u : 0u) << e;
    }
    *(unsigned short*)(masks + (size_t)pA * 32 + w * 2) = (unsigned short)ma;
    *(unsigned short*)(masks + (size_t)pB * 32 + w * 2) = (unsigned short)mb;
  }
  __syncthreads();

  // ---- hidden layers: single fp32 accumulator per element, k ascending, fmaf
  for (int l = 0; l < 4; ++l) {
    const float* Wl = Wh + (size_t)l * 65536 + c0;   // + uniform col offset
    float accA[16] = {};
    float accB[16] = {};
#pragma unroll 2
    for (int k = 0; k < 256; ++k) {
      float hA = hT[lane * SH + k];          // per-lane LDS, conflict-free
      float hB = hT[(64 + lane) * SH + k];
      const float* wr = Wl + k * 256;        // wave-uniform -> s_load_dwordx16
#pragma unroll
      for (int e = 0; e < 16; ++e) {
        float wv = wr[e];
        accA[e] = fmaf(hA, wv, accA[e]);
        accB[e] = fmaf(hB, wv, accB[e]);
      }
    }
    __syncthreads();                   // all hT reads done before overwrite
    unsigned ma = 0, mb = 0;
    float hnA[16], hnB[16];
#pragma unroll
    for (int e = 0; e < 16; ++e) {
      float bb = b_h[l * 256 + c0 + e];
      float aa = accA[e] + bb;
      bool posa = aa > 0.f;
      hnA[e] = posa ? aa : 0.f;
      ma |= (posa ? 1u : 0u) << e;
      float ab = accB[e] + bb;
      bool posb = ab > 0.f;
      hnB[e] = posb ? ab : 0.f;
      mb |= (posb ? 1u : 0u) << e;
    }
    *(unsigned short*)(masks + ((size_t)(l + 1) * NPTS + pA) * 32 + w * 2) =
        (unsigned short)ma;
    *(unsigned short*)(masks + ((size_t)(l + 1) * NPTS + pB) * 32 + w * 2) =
        (unsigned short)mb;
#pragma unroll
    for (int e = 0; e < 16; ++e) {
      hT[lane * SH + c0 + e] = hnA[e];
      hT[(64 + lane) * SH + c0 + e] = hnB[e];
    }
    __syncthreads();
  }

  // ---- p = h5 . Wout[:,1] + b_out[1]
  {
    float sA = 0.f, sB = 0.f;
#pragma unroll
    for (int e = 0; e < 16; ++e) {
      float wv = Wout[2 * (c0 + e) + 1];
      sA = fmaf(hT[lane * SH + c0 + e], wv, sA);
      sB = fmaf(hT[(64 + lane) * SH + c0 + e], wv, sB);
    }
    pscr[w][lane] = sA;
    pscr[w][64 + lane] = sB;
  }
  __syncthreads();
  if (tid < 128) {
    float s2 = 0.f;
#pragma unroll
    for (int g = 0; g < 16; ++g) s2 += pscr[g][tid];
    out[2 * NPTS + p0 + tid] = s2 + b_out[1];
  }
}

// ---------------------------------------------------------------- prep: Wh fp32 [l][k][n] -> f16 [l][n][k]
__global__ void __launch_bounds__(256) prep_weights_kernel(
    const float* __restrict__ Wh, _Float16* __restrict__ Wt) {
  int i = blockIdx.x * 256 + threadIdx.x;   // 0..262143
  int l = i >> 16;
  int rem = i & 65535;
  int k = rem >> 8, n = rem & 255;
  Wt[(size_t)(l << 16) + n * 256 + k] = (_Float16)Wh[i];
}

// ---------------------------------------------------------------- fused tangent chain (init + 4 layers + finalize)
// Block: 256 thr = 4 waves. 32 points -> 64 rows (0..31 x-tangent, 32..63 y).
// Tile M=64 x N=256; wave wn owns 64 rows x 64 cols. T lives in Apan (f16).
// v19: mfma(bf, af, acc) OPERAND SWAP -> D[row = n-local quad*4+reg]
// [col = m-local l15]: lane holds 4 consecutive n for one row m ->
// write-back is 16 x ds_write_b64. Finalize = MFMA chain with zero-padded
// f16 Wout B-fragment. B staging = v15 wave-private (barrier-free).
// mfma_f32_16x16x32_f16: A[m=lane&15][k=quad*8+j], B[k=quad*8+j][n=lane&15],
//                        D[row=quad*4+reg][col=lane&15]  (verified layouts)
__global__ void __launch_bounds__(256, 2) tangent_fused_kernel(
    const float* __restrict__ Win,
    const _Float16* __restrict__ Wt,          // [l][n][k] (pre-transposed)
    const unsigned int* __restrict__ maskDw,  // [5][NPTS][8] dwords
    const float* __restrict__ Wout, float* __restrict__ out) {
  constexpr int SA = 264;   // A row stride (halves): 256 + 8 pad
  constexpr int SB = 72;    // B row stride (halves): 64 + 8 pad
  __shared__ alignas(16) _Float16 Apan[64 * SA];        // 33792 B
  __shared__ alignas(16) _Float16 Bpan[4][64 * SB];     // 36864 B
  __shared__ unsigned int smask[5 * 256];               // 5120 B

  const int tid = threadIdx.x;
  const int lane = tid & 63;
  const int wn = tid >> 6;          // wave = 64-col group
  const int l15 = lane & 15, quad = lane >> 4;
  const int p0 = blockIdx.x * 32;   // 32 points per block

  // ---- stage all 5 mask layers (32 pts x 8 dw each)
#pragma unroll
  for (int i = 0; i < 5; ++i)
    smask[i * 256 + tid] = maskDw[(size_t)i * NPTS * 8 + (size_t)p0 * 8 + tid];
  __syncthreads();

  // ---- init T1 into Apan: row<32 -> x-tangent (Win row 0), row>=32 -> y (row 1)
#pragma unroll
  for (int i = 0; i < 8; ++i) {
    int g = tid + 256 * i;          // 0..2047 col-groups of 8
    int row = g >> 5, cg = g & 31;
    int c0 = cg * 8, pt = row & 31, tg = row >> 5;
    unsigned dw = smask[pt * 8 + (c0 >> 5)];
    half8_t v;
#pragma unroll
    for (int e = 0; e < 8; ++e) {
      bool m = (dw >> ((cg & 3) * 8 + e)) & 1;
      v[e] = m ? (_Float16)Win[tg * 256 + c0 + e] : (_Float16)0.f;
    }
    *(half8_t*)&Apan[row * SA + c0] = v;
  }
  __syncthreads();                  // Apan init visible to all waves

  // ---- 4 layers: acc = A @ W_l (computed transposed), gate, back into Apan
  for (int l = 0; l < 4; ++l) {
    const _Float16* Bw = Wt + (size_t)l * 65536 + (size_t)(wn * 64) * 256;
    _Float16* Bp = &Bpan[wn][0];
    floatx4 acc[4][4] = {};   // [mi][nj], element = D[n-local][m-local]
#pragma unroll
    for (int kp = 0; kp < 4; ++kp) {
      // wave-private B staging (no barrier; within-wave lgkmcnt ordering)
#pragma unroll
      for (int i = 0; i < 8; ++i) {
        int idx = lane + 64 * i;    // 0..511 half8 segs
        int row = idx >> 3, seg = idx & 7;
        *(half8_t*)&Bp[row * SB + seg * 8] =
            *(const half8_t*)(Bw + (size_t)row * 256 + kp * 64 + seg * 8);
      }
#pragma unroll
      for (int ks = 0; ks < 2; ++ks) {
        half8_t af[4], bf[4];
#pragma unroll
        for (int mi = 0; mi < 4; ++mi)
          af[mi] = *(const half8_t*)&Apan[(mi * 16 + l15) * SA + kp * 64 + ks * 32 + quad * 8];
#pragma unroll
        for (int nj = 0; nj < 4; ++nj)
          bf[nj] = *(const half8_t*)&Bp[(nj * 16 + l15) * SB + ks * 32 + quad * 8];
        // SWAPPED operands: same products/order (bit-identical values),
        // transposed D layout (lane = one T-row m, 4 consecutive n per reg)
#pragma unroll
        for (int mi = 0; mi < 4; ++mi)
#pragma unroll
          for (int nj = 0; nj < 4; ++nj)
            acc[mi][nj] = __builtin_amdgcn_mfma_f32_16x16x32_f16(bf[nj], af[mi], acc[mi][nj], 0, 0, 0);
      }
    }
    __syncthreads();          // all Apan reads of this layer done
    // gated write-back: lane (l15,quad) of tile (mi,nj) holds rows m=mi*16+l15,
    // cols C = wn*64 + nj*16 + quad*4 + r  -> one b64 per (mi,nj)
    const unsigned int* ml = &smask[(l + 1) * 256];
    uint2 mA = *(const uint2*)&ml[l15 * 8 + wn * 2];         // pt = l15
    uint2 mB = *(const uint2*)&ml[(16 + l15) * 8 + wn * 2];  // pt = 16+l15
#pragma unroll
    for (int mi = 0; mi < 4; ++mi) {
      uint2 md = (mi & 1) ? mB : mA;
      int m = mi * 16 + l15;
#pragma unroll
      for (int nj = 0; nj < 4; ++nj) {
        unsigned dw = (nj < 2) ? md.x : md.y;
        int bitbase = (nj & 1) * 16 + quad * 4;
        half4_t v;
#pragma unroll
        for (int r = 0; r < 4; ++r)
          v[r] = ((dw >> (bitbase + r)) & 1) ? (_Float16)acc[mi][nj][r]
                                             : (_Float16)0.f;
        *(half4_t*)&Apan[m * SA + wn * 64 + nj * 16 + quad * 4] = v;
      }
    }
    __syncthreads();
  }

  // ---- finalize: T5 @ Wout via one MFMA chain per wave (rows wn*16..+15)
  {
    floatx4 facc = {0.f, 0.f, 0.f, 0.f};
#pragma unroll
    for (int kc = 0; kc < 8; ++kc) {
      half8_t a = *(const half8_t*)&Apan[(wn * 16 + l15) * SA + kc * 32 + quad * 8];
      half8_t b;
#pragma unroll
      for (int j = 0; j < 8; ++j) {
        int k = kc * 32 + quad * 8 + j;
        b[j] = (l15 < 2) ? (_Float16)Wout[2 * k + l15] : (_Float16)0.f;
      }
      facc = __builtin_amdgcn_mfma_f32_16x16x32_f16(a, b, facc, 0, 0, 0);
    }
    // D[row=quad*4+r][col=l15]: global row = wn*16 + quad*4 + r; col 0 -> psi
    // derivative dot (u/v), col 1 -> p derivative dot (f/g)
    if (l15 < 2) {
#pragma unroll
      for (int r = 0; r < 4; ++r) {
        int row = wn * 16 + quad * 4 + r;
        int pt = p0 + (row & 31);
        float val = facc[r];
        if (l15 == 0) {
          if (row < 32) out[NPTS + pt] = -val;      // v = -psi_x
          else          out[pt] = val;              // u =  psi_y
        } else {
          if (row < 32) out[3 * NPTS + pt] = val;   // f = p_x
          else          out[4 * NPTS + pt] = val;   // g = p_y
        }
      }
    }
  }
}

// ---------------------------------------------------------------- launch
extern "C" void kernel_launch(void* const* d_in, const int* in_sizes, int n_in,
                              void* d_out, int out_size, void* d_ws, size_t ws_size,
                              hipStream_t stream) {
  const float* x = (const float*)d_in[0];
  const float* y = (const float*)d_in[1];
  const float* t = (const float*)d_in[2];
  const float* Win = (const float*)d_in[3];
  const float* b_in = (const float*)d_in[4];
  const float* Wh = (const float*)d_in[5];
  const float* b_h = (const float*)d_in[6];
  const float* Wout = (const float*)d_in[7];
  const float* b_out = (const float*)d_in[8];
  float* out = (float*)d_out;

  char* ws = (char*)d_ws;
  constexpr size_t MASK_SZ = (size_t)NPTS * 32;       // 2 MB per layer
  unsigned char* masks = (unsigned char*)ws;
  _Float16* Wt = (_Float16*)(ws + 5 * MASK_SZ);

  // weight transpose/cast first (independent of fwd)
  prep_weights_kernel<<<1024, 256, 0, stream>>>(Wh, Wt);

  // fp32 np-exact forward: masks L0..L4 + p
  fwd_fused_kernel<<<NPTS / 128, 1024, 0, stream>>>(
      x, y, t, Win, b_in, Wh, b_h, Wout, b_out, masks, out);

  // fused tangent chain: init + 4 MFMA layers + finalize (u,v,f,g)
  tangent_fused_kernel<<<NPTS / 32, 256, 0, stream>>>(
      Win, Wt, (const unsigned int*)masks, Wout, out);
}